// Round 1
// baseline (1146.236 us; speedup 1.0000x reference)
//
#include <hip/hip_runtime.h>
#include <hip/hip_bf16.h>

// ---------------------------------------------------------------------------
// Llama decode self-attention, B=32, S=1, DIM=4096, 32 q-heads, 8 kv-heads,
// HEAD_DIM=128, START_POS=2047 (attend over 2048 positions).
// Reference quirks matched: RoPE applied to xk AND xv, NOT xq.
// ---------------------------------------------------------------------------

#define START_POS_C 2047
#define SEQ_LEN 2048
#define NSPLIT 8          // k-split for GEMMs and seq-split for attention

// ---------------------------------------------------------------------------
// Skinny GEMM: part[split][b][m] = sum_{k in split} W[m,k] * x[b,k]
// W: [M, 4096] row-major, x: [32, 4096] row-major.
// Block tile: 128 rows x 32 batches; thread micro-tile 4x4.
// grid = (M/128, NSPLIT), block = 256.
// ---------------------------------------------------------------------------
__global__ __launch_bounds__(256) void gemm_part(
    const float* __restrict__ W, const float* __restrict__ x,
    float* __restrict__ part, int K, int klen)
{
    __shared__ float Wt[128 * 36];   // pad 36 floats/row
    __shared__ float xt[32 * 36];

    const int t  = threadIdx.x;
    const int rg = t >> 3;           // 0..31 (row group)
    const int bg = t & 7;            // 0..7  (batch group)
    const int M  = gridDim.x * 128;
    const int m0 = blockIdx.x * 128;
    const int k0 = blockIdx.y * klen;

    float acc[4][4];
#pragma unroll
    for (int i = 0; i < 4; ++i)
#pragma unroll
        for (int j = 0; j < 4; ++j) acc[i][j] = 0.f;

    const int xrow = t >> 3;         // 0..31
    const int xkk  = (t & 7) << 2;   // 0..28

    for (int kc = k0; kc < k0 + klen; kc += 32) {
        // stage W tile: 128 rows x 32 floats (1024 float4, 4 per thread)
#pragma unroll
        for (int p = 0; p < 4; ++p) {
            const int idx = t + (p << 8);
            const int row = idx >> 3;
            const int kk  = (idx & 7) << 2;
            const float4 w4 = *(const float4*)&W[(size_t)(m0 + row) * K + kc + kk];
            *(float4*)&Wt[row * 36 + kk] = w4;
        }
        // stage x tile: 32 rows x 32 floats (256 float4, 1 per thread)
        const float4 x4 = *(const float4*)&x[(size_t)xrow * K + kc + xkk];
        *(float4*)&xt[xrow * 36 + xkk] = x4;
        __syncthreads();

#pragma unroll
        for (int k4 = 0; k4 < 8; ++k4) {
            float4 wf[4], xf[4];
#pragma unroll
            for (int rr = 0; rr < 4; ++rr)
                wf[rr] = *(const float4*)&Wt[(rg + 32 * rr) * 36 + (k4 << 2)];
#pragma unroll
            for (int bb = 0; bb < 4; ++bb)
                xf[bb] = *(const float4*)&xt[(bg + 8 * bb) * 36 + (k4 << 2)];
#pragma unroll
            for (int rr = 0; rr < 4; ++rr)
#pragma unroll
                for (int bb = 0; bb < 4; ++bb) {
                    acc[rr][bb] = fmaf(wf[rr].x, xf[bb].x, acc[rr][bb]);
                    acc[rr][bb] = fmaf(wf[rr].y, xf[bb].y, acc[rr][bb]);
                    acc[rr][bb] = fmaf(wf[rr].z, xf[bb].z, acc[rr][bb]);
                    acc[rr][bb] = fmaf(wf[rr].w, xf[bb].w, acc[rr][bb]);
                }
        }
        __syncthreads();
    }

    // part layout [split][b][m] -> coalesced consumer reads
    float* po = part + (size_t)blockIdx.y * 32 * M;
#pragma unroll
    for (int bb = 0; bb < 4; ++bb)
#pragma unroll
        for (int rr = 0; rr < 4; ++rr)
            po[(size_t)(bg + 8 * bb) * M + (m0 + rg + 32 * rr)] = acc[rr][bb];
}

// ---------------------------------------------------------------------------
// Reduce k-split partials for q/k/v; fuse RoPE into k and v.
// part_q at part[0]          : [8][32][4096]
// part_k at part + 8*32*4096 : [8][32][1024]
// part_v at part_k + 8*32*1024
// ---------------------------------------------------------------------------
__global__ __launch_bounds__(256) void reduce_qkv(
    const float* __restrict__ part,
    const float* __restrict__ cosb, const float* __restrict__ sinb,
    float* __restrict__ qbuf, float* __restrict__ kbuf, float* __restrict__ vbuf)
{
    const int tid = blockIdx.x * 256 + threadIdx.x;
    const int NQ  = 32 * 4096;
    const int NKP = 32 * 512;  // pairs per tensor

    if (tid < NQ) {
        const int b = tid >> 12, o = tid & 4095;
        float s = 0.f;
#pragma unroll
        for (int sp = 0; sp < NSPLIT; ++sp)
            s += part[((size_t)sp * 32 + b) * 4096 + o];
        qbuf[tid] = s;  // qbuf[b*4096 + o]
    } else if (tid < NQ + 2 * NKP) {
        const int isV = (tid >= NQ + NKP) ? 1 : 0;
        const int i = tid - NQ - (isV ? NKP : 0);
        const float* pp = part + (size_t)NSPLIT * 32 * 4096
                               + (isV ? (size_t)NSPLIT * 32 * 1024 : 0);
        const int b = i >> 9, p = i & 511;  // pair index within 1024 dims
        float re = 0.f, im = 0.f;
#pragma unroll
        for (int sp = 0; sp < NSPLIT; ++sp) {
            const float2 v2 = *(const float2*)&pp[((size_t)sp * 32 + b) * 1024 + 2 * p];
            re += v2.x; im += v2.y;
        }
        const float c = cosb[p & 63], sn = sinb[p & 63];
        float* ob = isV ? vbuf : kbuf;
        ob[b * 1024 + 2 * p]     = re * c - im * sn;
        ob[b * 1024 + 2 * p + 1] = re * sn + im * c;
    }
}

// ---------------------------------------------------------------------------
// Flash-decode attention partial. grid = (NSPLIT, 8 kvh, 32 b), block = 256.
// Wave w handles q-head h = kvh*4 + w. Each split covers 256 positions.
// Position 2047 sourced from new (roped) kbuf/vbuf instead of cache.
// opart layout: [b][h][split][130]  (128 dims of o, then m, then l)
// ---------------------------------------------------------------------------
__global__ __launch_bounds__(256) void attn_partial(
    const float* __restrict__ qbuf, const float* __restrict__ kbuf,
    const float* __restrict__ vbuf, const float* __restrict__ kcache,
    const float* __restrict__ vcache, float* __restrict__ opart)
{
    const int split = blockIdx.x;
    const int kvh   = blockIdx.y;
    const int b     = blockIdx.z;
    const int t     = threadIdx.x;
    const int wave  = t >> 6, lane = t & 63;
    const int h     = kvh * 4 + wave;

    __shared__ float KT[64 * 132];    // K/V tile, pad 132 floats/row
    __shared__ float q_s[4][128];
    __shared__ float p_s[4][256];

    // each wave loads its own head's q
    const float2 q2 = *(const float2*)&qbuf[(size_t)b * 4096 + h * 128 + lane * 2];
    q_s[wave][lane * 2]     = q2.x;
    q_s[wave][lane * 2 + 1] = q2.y;

    const int j0base = split * 256;
    float sc[4];

    // Pass 1: scores. Lane l owns position (tile_base + l).
#pragma unroll
    for (int tt = 0; tt < 4; ++tt) {
        const int j0 = j0base + tt * 64;
        __syncthreads();   // previous tile fully consumed / q_s visible
#pragma unroll
        for (int p = 0; p < 8; ++p) {
            const int idx = t + (p << 8);          // 0..2047
            const int jr  = idx >> 5;              // 0..63
            const int dq  = (idx & 31) << 2;       // 0..124
            const int j   = j0 + jr;
            const float* src = (j == START_POS_C)
                ? &kbuf[(size_t)b * 1024 + kvh * 128 + dq]
                : &kcache[(((size_t)b * 4096 + j) * 8 + kvh) * 128 + dq];
            *(float4*)&KT[jr * 132 + dq] = *(const float4*)src;
        }
        __syncthreads();

        float acc = 0.f;
        const float* krow = &KT[lane * 132];
#pragma unroll
        for (int i = 0; i < 32; ++i) {
            const float4 kv = *(const float4*)&krow[i * 4];
            const float4 qv = *(const float4*)&q_s[wave][i * 4];
            acc = fmaf(kv.x, qv.x, acc);
            acc = fmaf(kv.y, qv.y, acc);
            acc = fmaf(kv.z, qv.z, acc);
            acc = fmaf(kv.w, qv.w, acc);
        }
        sc[tt] = acc * 0.08838834764831845f;   // 1/sqrt(128)
    }
    __syncthreads();

    // per-wave softmax partial over this split's 256 positions
    float m = fmaxf(fmaxf(sc[0], sc[1]), fmaxf(sc[2], sc[3]));
#pragma unroll
    for (int off = 32; off > 0; off >>= 1) m = fmaxf(m, __shfl_xor(m, off));
    float pv[4]; float lsum = 0.f;
#pragma unroll
    for (int tt = 0; tt < 4; ++tt) { pv[tt] = __expf(sc[tt] - m); lsum += pv[tt]; }
#pragma unroll
    for (int off = 32; off > 0; off >>= 1) lsum += __shfl_xor(lsum, off);
#pragma unroll
    for (int tt = 0; tt < 4; ++tt) p_s[wave][tt * 64 + lane] = pv[tt];

    // Pass 2: PV. Lane l owns dims l and l+64.
    float o0 = 0.f, o1 = 0.f;
#pragma unroll
    for (int tt = 0; tt < 4; ++tt) {
        const int j0 = j0base + tt * 64;
#pragma unroll
        for (int p = 0; p < 8; ++p) {
            const int idx = t + (p << 8);
            const int jr  = idx >> 5;
            const int dq  = (idx & 31) << 2;
            const int j   = j0 + jr;
            const float* src = (j == START_POS_C)
                ? &vbuf[(size_t)b * 1024 + kvh * 128 + dq]
                : &vcache[(((size_t)b * 4096 + j) * 8 + kvh) * 128 + dq];
            *(float4*)&KT[jr * 132 + dq] = *(const float4*)src;
        }
        __syncthreads();
#pragma unroll 8
        for (int jr = 0; jr < 64; ++jr) {
            const float p = p_s[wave][tt * 64 + jr];
            o0 = fmaf(p, KT[jr * 132 + lane], o0);
            o1 = fmaf(p, KT[jr * 132 + 64 + lane], o1);
        }
        __syncthreads();
    }

    float* op = opart + (((size_t)b * 32 + h) * NSPLIT + split) * 130;
    op[lane]      = o0;
    op[64 + lane] = o1;
    if (lane == 0) { op[128] = m; op[129] = lsum; }
}

// ---------------------------------------------------------------------------
// Combine split partials -> attn output (b, h, d) = [32, 4096]
// grid = 1024 (b*32+h), block = 128 (d)
// ---------------------------------------------------------------------------
__global__ __launch_bounds__(128) void attn_combine(
    const float* __restrict__ opart, float* __restrict__ attnb)
{
    const int bh = blockIdx.x;
    const int d  = threadIdx.x;
    const float* base = opart + (size_t)bh * NSPLIT * 130;

    float M = -1e30f;
#pragma unroll
    for (int s = 0; s < NSPLIT; ++s) M = fmaxf(M, base[s * 130 + 128]);
    float L = 0.f, o = 0.f;
#pragma unroll
    for (int s = 0; s < NSPLIT; ++s) {
        const float w = __expf(base[s * 130 + 128] - M);
        L += base[s * 130 + 129] * w;
        o += w * base[s * 130 + d];
    }
    attnb[(size_t)bh * 128 + d] = o / L;
}

// ---------------------------------------------------------------------------
// Final reduce of wo k-split partials -> d_out [32, 4096]
// ---------------------------------------------------------------------------
__global__ __launch_bounds__(256) void reduce_out(
    const float* __restrict__ part, float* __restrict__ out)
{
    const int tid = blockIdx.x * 256 + threadIdx.x;  // 0..131071
    const int b = tid >> 12, o = tid & 4095;
    float s = 0.f;
#pragma unroll
    for (int sp = 0; sp < NSPLIT; ++sp)
        s += part[((size_t)sp * 32 + b) * 4096 + o];
    out[tid] = s;
}

extern "C" void kernel_launch(void* const* d_in, const int* in_sizes, int n_in,
                              void* d_out, int out_size, void* d_ws, size_t ws_size,
                              hipStream_t stream)
{
    const float* x    = (const float*)d_in[0];
    // d_in[1] = start_pos (always 2047, baked in)
    const float* cosb = (const float*)d_in[2];
    const float* sinb = (const float*)d_in[3];
    const float* wq   = (const float*)d_in[4];
    const float* wk   = (const float*)d_in[5];
    const float* wv   = (const float*)d_in[6];
    const float* wo   = (const float*)d_in[7];
    const float* kc   = (const float*)d_in[8];
    const float* vc   = (const float*)d_in[9];

    float* ws = (float*)d_ws;
    // workspace layout (floats)
    float* part  = ws;                    // 8*32*4096 + 2 * 8*32*1024 = 1,572,864 (reused for wo)
    float* qbuf  = ws + 1572864;          // 131072
    float* kbuf  = qbuf + 131072;         // 32768
    float* vbuf  = kbuf + 32768;          // 32768
    float* op    = vbuf + 32768;          // 32*32*8*130 = 1,064,960
    float* attnb = op + 1064960;          // 131072   (total ~11.9 MB)

    float* part_k = part + (size_t)NSPLIT * 32 * 4096;
    float* part_v = part_k + (size_t)NSPLIT * 32 * 1024;

    // QKV projections (k-split partials)
    gemm_part<<<dim3(32, NSPLIT), 256, 0, stream>>>(wq, x, part,   4096, 4096 / NSPLIT);
    gemm_part<<<dim3(8,  NSPLIT), 256, 0, stream>>>(wk, x, part_k, 4096, 4096 / NSPLIT);
    gemm_part<<<dim3(8,  NSPLIT), 256, 0, stream>>>(wv, x, part_v, 4096, 4096 / NSPLIT);

    // reduce + RoPE(k, v)
    reduce_qkv<<<640, 256, 0, stream>>>(part, cosb, sinb, qbuf, kbuf, vbuf);

    // flash-decode attention over 2048 positions, split 8 ways
    attn_partial<<<dim3(NSPLIT, 8, 32), 256, 0, stream>>>(qbuf, kbuf, vbuf, kc, vc, op);
    attn_combine<<<1024, 128, 0, stream>>>(op, attnb);

    // output projection
    gemm_part<<<dim3(32, NSPLIT), 256, 0, stream>>>(wo, attnb, part, 4096, 4096 / NSPLIT);
    reduce_out<<<512, 256, 0, stream>>>(part, (float*)d_out);
}